// Round 2
// baseline (172.286 us; speedup 1.0000x reference)
//
#include <hip/hip_runtime.h>

// out[p, :] = W[i1[p], :] + (i1[p] != i2[p] ? W[i2[p], :] : 0)
// P = B*S = 32768 positions, D = 512 fp32 = 128 float4 per row.
// v3: v2 structure (4 float4/thread, 32 threads/position, nontemporal
//     stores) with the out_size semantics fixed: out_size is the f32
//     ELEMENT count (B*S*512), not bytes. total_pos = out_size / 512.

#define EMB_DIM 512
#define QUADS_PER_ROW (EMB_DIM / 4)   // 128
#define QPT 4                         // float4 per thread
#define TPP (QUADS_PER_ROW / QPT)     // 32 threads per position

typedef float f4 __attribute__((ext_vector_type(4)));

__global__ __launch_bounds__(256) void twohot_kernel(
    const int* __restrict__ idx1,
    const int* __restrict__ idx2,
    const f4*  __restrict__ w4,    // [VOCAB * 128]
    f4*        __restrict__ out4,  // [P * 128]
    int total_pos)
{
    int gid = blockIdx.x * blockDim.x + threadIdx.x;
    int pos = gid >> 5;              // gid / TPP
    int q   = gid & (TPP - 1);       // gid % TPP
    if (pos >= total_pos) return;

    int i1 = idx1[pos];
    int i2 = idx2[pos];

    // Row 1: 4 independent 16B gathers (offsets fold to immediates).
    const f4* r1 = w4 + (long)i1 * QUADS_PER_ROW + q;
    f4 v0 = r1[0 * TPP];
    f4 v1 = r1[1 * TPP];
    f4 v2 = r1[2 * TPP];
    f4 v3 = r1[3 * TPP];

    // Row 2 only when distinct (P(equal) ~ 1/50257 -> essentially no divergence).
    if (i2 != i1) {
        const f4* r2 = w4 + (long)i2 * QUADS_PER_ROW + q;
        f4 u0 = r2[0 * TPP];
        f4 u1 = r2[1 * TPP];
        f4 u2 = r2[2 * TPP];
        f4 u3 = r2[3 * TPP];
        v0 += u0; v1 += u1; v2 += u2; v3 += u3;
    }

    // Write-once output: nontemporal so it doesn't evict weight rows in L2.
    f4* o = out4 + (long)pos * QUADS_PER_ROW + q;
    __builtin_nontemporal_store(v0, o + 0 * TPP);
    __builtin_nontemporal_store(v1, o + 1 * TPP);
    __builtin_nontemporal_store(v2, o + 2 * TPP);
    __builtin_nontemporal_store(v3, o + 3 * TPP);
}

extern "C" void kernel_launch(void* const* d_in, const int* in_sizes, int n_in,
                              void* d_out, int out_size, void* d_ws, size_t ws_size,
                              hipStream_t stream) {
    const int* idx1 = (const int*)d_in[0];   // input_one [B,S] int32
    const int* idx2 = (const int*)d_in[1];   // input_two [B,S] int32
    const f4*  w4   = (const f4*)d_in[2];    // weight [VOCAB, 512] fp32
    f4* out4        = (f4*)d_out;            // [B,S,512] fp32

    int total_pos     = out_size / EMB_DIM;     // out_size = B*S*512 f32 elements
    int total_threads = total_pos * TPP;
    int block = 256;
    int grid  = (total_threads + block - 1) / block;
    twohot_kernel<<<grid, block, 0, stream>>>(idx1, idx2, w4, out4, total_pos);
}